// Round 5
// baseline (23.959 us; speedup 1.0000x reference)
//
#include <hip/hip_runtime.h>

// out[k][j] = max( x1[k][j], max_i( W[i][j]*x0[k][i] + B[i][j] + C_norm[i][j] ) )
// N=4096, D=256, f32 in/out. Math in packed f16; abs err ~0.03 << 0.101.
//
// prep: convert x0 / W / (B+C) to f16 in d_ws (memory-bound, ~1.3us).
// main: 256 blocks x 512 thr; whole-i LDS resident (96KB); ONE stage, ONE
// barrier, then pure compute: 2048 pk insts + 96 conflict-free ds_read_b128
// per thread. 8 waves split i 8-ways; LDS tree-merge; distributed epilogue.

typedef _Float16 h16;
typedef h16 h2  __attribute__((ext_vector_type(2)));
typedef h16 h8v __attribute__((ext_vector_type(8)));
typedef float f32x4 __attribute__((ext_vector_type(4)));

constexpr int Dk = 256;

// ---------------- prep: f32 -> f16 ----------------
__global__ __launch_bounds__(256)
void prep(const float* __restrict__ x0, const float* __restrict__ Cn,
          const float* __restrict__ W, const float* __restrict__ Bm,
          h16* __restrict__ x0h, h16* __restrict__ Wh, h16* __restrict__ Ah) {
  const int b = blockIdx.x;
  const int t = threadIdx.x;
  if (b < 512) {                       // x0: 4096*256 elems, 8 per thread
    const int idx = (b * 256 + t) * 8;
    const f32x4 v0 = *reinterpret_cast<const f32x4*>(&x0[idx]);
    const f32x4 v1 = *reinterpret_cast<const f32x4*>(&x0[idx + 4]);
    h8v h;
#pragma unroll
    for (int u = 0; u < 4; ++u) { h[u] = (h16)v0[u]; h[u + 4] = (h16)v1[u]; }
    *reinterpret_cast<h8v*>(&x0h[idx]) = h;
  } else {                             // W and A=B+C: 256*256, 8 per thread
    const int idx = ((b - 512) * 256 + t) * 8;
    const f32x4 w0 = *reinterpret_cast<const f32x4*>(&W[idx]);
    const f32x4 w1 = *reinterpret_cast<const f32x4*>(&W[idx + 4]);
    const f32x4 b0 = *reinterpret_cast<const f32x4*>(&Bm[idx]);
    const f32x4 b1 = *reinterpret_cast<const f32x4*>(&Bm[idx + 4]);
    const f32x4 c0 = *reinterpret_cast<const f32x4*>(&Cn[idx]);
    const f32x4 c1 = *reinterpret_cast<const f32x4*>(&Cn[idx + 4]);
    const f32x4 a0 = b0 + c0, a1 = b1 + c1;
    h8v hw, ha;
#pragma unroll
    for (int u = 0; u < 4; ++u) {
      hw[u] = (h16)w0[u]; hw[u + 4] = (h16)w1[u];
      ha[u] = (h16)a0[u]; ha[u + 4] = (h16)a1[u];
    }
    *reinterpret_cast<h8v*>(&Wh[idx]) = hw;
    *reinterpret_cast<h8v*>(&Ah[idx]) = ha;
  }
}

// ---------------- main ----------------
__global__ __launch_bounds__(512, 1)
void mp_main(const h16* __restrict__ x0h, const h16* __restrict__ Wh,
             const h16* __restrict__ Ah, const float* __restrict__ x1,
             float* __restrict__ out) {
  __shared__ h16 Wl[256 * 64];   // [i][jj]        32KB
  __shared__ h16 Al[256 * 64];   // [i][jj]        32KB
  __shared__ h16 Xl[64 * 256];   // [kk][i] swz    32KB

  const int tid = threadIdx.x;
  const int w   = tid >> 6;          // wave 0..7 -> i-slice [32w, 32w+32)
  const int l   = tid & 63;
  const int tk  = l >> 3;            // 8 k's per lane-group
  const int tj  = l & 7;             // 8 j's per lane
  const int k0  = (blockIdx.x >> 2) * 64;
  const int j0  = (blockIdx.x & 3) * 64;

  // ---- stage (one shot): W/A tiles ----
#pragma unroll
  for (int c = 0; c < 4; ++c) {
    const int idx = c * 512 + tid;           // 2048 slots: row=idx>>3, col=(idx&7)*8
    const int row = idx >> 3;
    const int col = (idx & 7) * 8;
    *reinterpret_cast<h8v*>(&Wl[row * 64 + col]) =
        *reinterpret_cast<const h8v*>(&Wh[row * Dk + j0 + col]);
    *reinterpret_cast<h8v*>(&Al[row * 64 + col]) =
        *reinterpret_cast<const h8v*>(&Ah[row * Dk + j0 + col]);
  }
  // ---- stage x0 tile, XOR-swizzled columns ----
#pragma unroll
  for (int c = 0; c < 4; ++c) {
    const int idx = c * 512 + tid;           // 2048 slots: row=idx>>5, col=(idx&31)*8
    const int row = idx >> 5;
    const int col = (idx & 31) * 8;
    const int sw  = col ^ (((row >> 3) & 7) * 8);
    *reinterpret_cast<h8v*>(&Xl[row * 256 + sw]) =
        *reinterpret_cast<const h8v*>(&x0h[(k0 + row) * Dk + col]);
  }
  __syncthreads();

  h2 acc[8][4];
#pragma unroll
  for (int kk = 0; kk < 8; ++kk)
#pragma unroll
    for (int p = 0; p < 4; ++p)
      acc[kk][p] = h2{(h16)(-60000.0f), (h16)(-60000.0f)};

  const int ibase = 32 * w;

#define USTEP(U) {                                                              \
    const h8v wv = *reinterpret_cast<const h8v*>(&Wl[(ic + (U)) * 64 + tj * 8]);\
    const h8v av = *reinterpret_cast<const h8v*>(&Al[(ic + (U)) * 64 + tj * 8]);\
    const h2 wp0 = __builtin_shufflevector(wv, wv, 0, 1);                       \
    const h2 wp1 = __builtin_shufflevector(wv, wv, 2, 3);                       \
    const h2 wp2 = __builtin_shufflevector(wv, wv, 4, 5);                       \
    const h2 wp3 = __builtin_shufflevector(wv, wv, 6, 7);                       \
    const h2 ap0 = __builtin_shufflevector(av, av, 0, 1);                       \
    const h2 ap1 = __builtin_shufflevector(av, av, 2, 3);                       \
    const h2 ap2 = __builtin_shufflevector(av, av, 4, 5);                       \
    const h2 ap3 = __builtin_shufflevector(av, av, 6, 7);                       \
    _Pragma("unroll")                                                           \
    for (int kk = 0; kk < 8; ++kk) {                                            \
      const h2 xb = __builtin_shufflevector(xr[kk], xr[kk], (U), (U));          \
      acc[kk][0] = __builtin_elementwise_max(acc[kk][0], __builtin_elementwise_fma(wp0, xb, ap0)); \
      acc[kk][1] = __builtin_elementwise_max(acc[kk][1], __builtin_elementwise_fma(wp1, xb, ap1)); \
      acc[kk][2] = __builtin_elementwise_max(acc[kk][2], __builtin_elementwise_fma(wp2, xb, ap2)); \
      acc[kk][3] = __builtin_elementwise_max(acc[kk][3], __builtin_elementwise_fma(wp3, xb, ap3)); \
    }                                                                           \
  }

#pragma unroll
  for (int g = 0; g < 4; ++g) {
    const int ic = ibase + g * 8;
    h8v xr[8];
#pragma unroll
    for (int kk = 0; kk < 8; ++kk) {
      const int row = tk * 8 + kk;
      xr[kk] = *reinterpret_cast<const h8v*>(&Xl[row * 256 + (ic ^ (tk * 8))]);
    }
    USTEP(0) USTEP(1) USTEP(2) USTEP(3) USTEP(4) USTEP(5) USTEP(6) USTEP(7)
  }
#undef USTEP
  __syncthreads();   // compute done; Wl reusable as merge scratch

  // ---- tree merge across waves ----
  uint4* mrg = reinterpret_cast<uint4*>(Wl);
  auto wslot = [&](int s) {
#pragma unroll
    for (int kk = 0; kk < 8; ++kk) {
      uint4 u;
      u.x = __builtin_bit_cast(unsigned int, acc[kk][0]);
      u.y = __builtin_bit_cast(unsigned int, acc[kk][1]);
      u.z = __builtin_bit_cast(unsigned int, acc[kk][2]);
      u.w = __builtin_bit_cast(unsigned int, acc[kk][3]);
      mrg[(s * 8 + kk) * 64 + l] = u;
    }
  };
  auto rmerge = [&](int s) {
#pragma unroll
    for (int kk = 0; kk < 8; ++kk) {
      const uint4 u = mrg[(s * 8 + kk) * 64 + l];
      acc[kk][0] = __builtin_elementwise_max(acc[kk][0], __builtin_bit_cast(h2, u.x));
      acc[kk][1] = __builtin_elementwise_max(acc[kk][1], __builtin_bit_cast(h2, u.y));
      acc[kk][2] = __builtin_elementwise_max(acc[kk][2], __builtin_bit_cast(h2, u.z));
      acc[kk][3] = __builtin_elementwise_max(acc[kk][3], __builtin_bit_cast(h2, u.w));
    }
  };

  if (w >= 4) wslot(w - 4);
  __syncthreads();
  if (w < 4) rmerge(w);
  __syncthreads();
  if (w == 2 || w == 3) wslot(w - 2);
  __syncthreads();
  if (w < 2) rmerge(w);
  __syncthreads();
  if (w == 1) wslot(0);
  __syncthreads();
  if (w == 0) { rmerge(0); wslot(0); }
  __syncthreads();

  // ---- distributed epilogue ----
  {
    const uint4 u = mrg[w * 64 + l];   // contiguous: = mrg[tid]
    const h2 p0 = __builtin_bit_cast(h2, u.x);
    const h2 p1 = __builtin_bit_cast(h2, u.y);
    const h2 p2 = __builtin_bit_cast(h2, u.z);
    const h2 p3 = __builtin_bit_cast(h2, u.w);
    const int k = k0 + (l >> 3) * 8 + w;
    const int j = j0 + (l & 7) * 8;
    f32x4 o0 = { (float)p0[0], (float)p0[1], (float)p1[0], (float)p1[1] };
    f32x4 o1 = { (float)p2[0], (float)p2[1], (float)p3[0], (float)p3[1] };
    const f32x4* xg = reinterpret_cast<const f32x4*>(&x1[k * Dk + j]);
    o0 = __builtin_elementwise_max(o0, xg[0]);
    o1 = __builtin_elementwise_max(o1, xg[1]);
    f32x4* og = reinterpret_cast<f32x4*>(&out[k * Dk + j]);
    og[0] = o0;
    og[1] = o1;
  }
}

extern "C" void kernel_launch(void* const* d_in, const int* in_sizes, int n_in,
                              void* d_out, int out_size, void* d_ws, size_t ws_size,
                              hipStream_t stream) {
  const float* x0 = (const float*)d_in[0];
  const float* x1 = (const float*)d_in[1];
  const float* Cn = (const float*)d_in[2];
  const float* W  = (const float*)d_in[3];
  const float* Bm = (const float*)d_in[4];
  float* out = (float*)d_out;

  const int n = in_sizes[0] / Dk;                  // 4096
  h16* x0h = (h16*)d_ws;                           // 2 MB
  h16* Wh  = (h16*)((char*)d_ws + (size_t)n * Dk * 2);          // 128 KB
  h16* Ah  = (h16*)((char*)d_ws + (size_t)n * Dk * 2 + Dk * Dk * 2);

  hipLaunchKernelGGL(prep, dim3(512 + 32), dim3(256), 0, stream,
                     x0, Cn, W, Bm, x0h, Wh, Ah);
  hipLaunchKernelGGL(mp_main, dim3((n / 64) * 4), dim3(512), 0, stream,
                     x0h, Wh, Ah, x1, out);
}